// Round 7
// baseline (1364.047 us; speedup 1.0000x reference)
//
#include <hip/hip_runtime.h>
#include <hip/hip_cooperative_groups.h>

namespace cg = cooperative_groups;

#define HDIM 16
#define FIN 54

// ---------------------------------------------------------------------------
// Whole 2-layer GCN in one cooperative kernel. Phases split by grid.sync():
//  P0 zero cnt | P1 count deg | P2 dinv + zero agg | P3 gemm54 (x@W1)*dinv
//  P4 scatter1 | P5 finish1 (+relu, @W2 fused, *dinv, agg:=0) | P6 scatter2
//  P7 finish2 (+relu) -> out
// hs convention: hA/hB hold dinv[v] * t[v,:], so edge msg = hs[src] and
// finish computes relu(dinv_i*(agg_i + hs_i) + b).
// ---------------------------------------------------------------------------
__global__ __launch_bounds__(256, 8)
void fused_gcn(const float* __restrict__ x, const int* __restrict__ src,
               const int* __restrict__ dst,
               const float* __restrict__ W1, const float* __restrict__ b1,
               const float* __restrict__ W2, const float* __restrict__ b2,
               float* __restrict__ out,
               float* __restrict__ dinv, float* __restrict__ hA,
               float* __restrict__ hB, float* __restrict__ agg,
               int* __restrict__ cnt, int n, int E) {
    cg::grid_group grid = cg::this_grid();

    __shared__ float W1l[FIN * HDIM];    // 3456 B
    __shared__ float W2l[HDIM * HDIM];   // 1024 B
    for (int t = threadIdx.x; t < FIN * HDIM; t += blockDim.x) W1l[t] = W1[t];
    for (int t = threadIdx.x; t < HDIM * HDIM; t += blockDim.x) W2l[t] = W2[t];
    __syncthreads();

    const int gsz = (int)(gridDim.x * blockDim.x);
    const int tid = (int)(blockIdx.x * blockDim.x + threadIdx.x);
    const int n16 = n * HDIM;
    const long long e16 = (long long)E * HDIM;   // 51.2M

    // ---- P0: zero cnt ----
    for (int i = tid; i < n; i += gsz) cnt[i] = 0;
    grid.sync();

    // ---- P1: degree count (int atomics) ----
    for (int e = tid; e < E; e += gsz) atomicAdd(&cnt[dst[e]], 1);
    grid.sync();

    // ---- P2: dinv + zero agg ----
    for (int i = tid; i < n; i += gsz) dinv[i] = rsqrtf((float)cnt[i] + 1.0f);
    for (int i = tid; i < n16; i += gsz) agg[i] = 0.0f;
    grid.sync();

    // ---- P3: hA[row,:] = dinv[row] * (x[row,:] @ W1) ----
    for (int row = tid; row < n; row += gsz) {
        float acc[HDIM];
#pragma unroll
        for (int j = 0; j < HDIM; ++j) acc[j] = 0.0f;
        const float* xr = x + (size_t)row * FIN;
#pragma unroll
        for (int k = 0; k < FIN; ++k) {
            float xv = xr[k];
#pragma unroll
            for (int j = 0; j < HDIM; ++j)
                acc[j] = fmaf(xv, W1l[k * HDIM + j], acc[j]);
        }
        float di = dinv[row];
        float4* yo = (float4*)(hA + (size_t)row * HDIM);
        yo[0] = make_float4(di * acc[0], di * acc[1], di * acc[2], di * acc[3]);
        yo[1] = make_float4(di * acc[4], di * acc[5], di * acc[6], di * acc[7]);
        yo[2] = make_float4(di * acc[8], di * acc[9], di * acc[10], di * acc[11]);
        yo[3] = make_float4(di * acc[12], di * acc[13], di * acc[14], di * acc[15]);
    }
    grid.sync();

    // ---- P4: scatter layer 1: agg[d,:] += hA[s,:] ----
    for (long long idx = tid; idx < e16; idx += gsz) {
        int e = (int)(idx >> 4);
        int j = (int)(idx & 15);
        int s = src[e];
        int d = dst[e];
        atomicAdd(&agg[(size_t)d * HDIM + j], hA[(size_t)s * HDIM + j]);
    }
    grid.sync();

    // ---- P5: finish1: r=relu(dinv*(agg+hA)+b1); hB = dinv*(r@W2); agg=0 ----
    for (int idx = tid; idx < n16; idx += gsz) {
        int i = idx >> 4;
        int j = idx & 15;
        float di = dinv[i];
        float r = fmaxf(fmaf(di, agg[idx] + hA[idx], b1[j]), 0.0f);
        float o = 0.0f;
#pragma unroll
        for (int jj = 0; jj < HDIM; ++jj) {
            float rv = __shfl(r, jj, HDIM);   // 16-lane group = one node
            o = fmaf(rv, W2l[jj * HDIM + j], o);
        }
        hB[idx] = di * o;
        agg[idx] = 0.0f;                      // ready for layer 2
    }
    grid.sync();

    // ---- P6: scatter layer 2: agg[d,:] += hB[s,:] ----
    for (long long idx = tid; idx < e16; idx += gsz) {
        int e = (int)(idx >> 4);
        int j = (int)(idx & 15);
        int s = src[e];
        int d = dst[e];
        atomicAdd(&agg[(size_t)d * HDIM + j], hB[(size_t)s * HDIM + j]);
    }
    grid.sync();

    // ---- P7: finish2 -> out ----
    for (int idx = tid; idx < n16; idx += gsz) {
        int i = idx >> 4;
        int j = idx & 15;
        float di = dinv[i];
        out[idx] = fmaxf(fmaf(di, agg[idx] + hB[idx], b2[j]), 0.0f);
    }
}

extern "C" void kernel_launch(void* const* d_in, const int* in_sizes, int n_in,
                              void* d_out, int out_size, void* d_ws, size_t ws_size,
                              hipStream_t stream) {
    const float* x  = (const float*)d_in[0];   // [n, 54]
    const int*   ei = (const int*)d_in[1];     // [2, E]
    const float* W1 = (const float*)d_in[2];   // [54, 16]
    const float* b1 = (const float*)d_in[3];   // [16]
    const float* W2 = (const float*)d_in[4];   // [16, 16]
    const float* b2 = (const float*)d_in[5];   // [16]
    float* out = (float*)d_out;

    int E = in_sizes[1] / 2;                   // 3,200,000
    int n = in_sizes[0] / FIN;                 // 100,000
    const int* src = ei;
    const int* dst = ei + E;

    char* w = (char*)d_ws;
    float* dinv = (float*)w;                   w += (size_t)n * 4;
    float* hA   = (float*)w;                   w += (size_t)n * HDIM * 4;
    float* hB   = (float*)w;                   w += (size_t)n * HDIM * 4;
    float* agg  = (float*)w;                   w += (size_t)n * HDIM * 4;
    int*   cnt  = (int*)w;                     // n ints   (total ~20 MB)

    // size the cooperative grid to exactly fill the device
    int numCU = 0, bpc = 0;
    hipDeviceGetAttribute(&numCU, hipDeviceAttributeMultiprocessorCount, 0);
    hipOccupancyMaxActiveBlocksPerMultiprocessor(&bpc, (const void*)fused_gcn, 256, 0);
    if (numCU <= 0) numCU = 256;
    if (bpc <= 0) bpc = 4;
    dim3 gridDim((unsigned)(numCU * bpc)), blockDim(256);

    void* args[] = {
        (void*)&x, (void*)&src, (void*)&dst,
        (void*)&W1, (void*)&b1, (void*)&W2, (void*)&b2,
        (void*)&out,
        (void*)&dinv, (void*)&hA, (void*)&hB, (void*)&agg, (void*)&cnt,
        (void*)&n, (void*)&E,
    };
    hipLaunchCooperativeKernel((const void*)fused_gcn, gridDim, blockDim,
                               args, 0, stream);
}

// Round 8
// 617.075 us; speedup vs baseline: 2.2105x; 2.2105x over previous
//
#include <hip/hip_runtime.h>

#define HDIM 16
#define FIN 54

// ---------------------------------------------------------------------------
// cnt[dst] += 1 (int atomics, payload-only write traffic)
// ---------------------------------------------------------------------------
__global__ void count_kernel(const int* __restrict__ dst, int* __restrict__ cnt, int E) {
    int e = blockIdx.x * blockDim.x + threadIdx.x;
    if (e < E) atomicAdd(&cnt[dst[e]], 1);
}

// ---------------------------------------------------------------------------
// exclusive scan of cnt (in place) + fused dinv = rsqrt(deg+1) from pre-scan vals
// 256 threads x 16 = 4096 elems per block
// ---------------------------------------------------------------------------
__global__ void scan1_kernel(int* __restrict__ data, int* __restrict__ bsum,
                             float* __restrict__ dinv, int n) {
    __shared__ int sh[256];
    int off = blockIdx.x * 4096 + threadIdx.x * 16;
    int vals[16];
    int local = 0;
#pragma unroll
    for (int k = 0; k < 16; ++k) {
        int v = (off + k < n) ? data[off + k] : 0;
        vals[k] = v;
        local += v;
        if (off + k < n) dinv[off + k] = rsqrtf((float)v + 1.0f);
    }
    sh[threadIdx.x] = local;
    __syncthreads();
#pragma unroll
    for (int d = 1; d < 256; d <<= 1) {
        int t = (threadIdx.x >= d) ? sh[threadIdx.x - d] : 0;
        __syncthreads();
        sh[threadIdx.x] += t;
        __syncthreads();
    }
    int run = (threadIdx.x == 0) ? 0 : sh[threadIdx.x - 1];
#pragma unroll
    for (int k = 0; k < 16; ++k) {
        if (off + k < n) data[off + k] = run;
        run += vals[k];
    }
    if (threadIdx.x == 0) bsum[blockIdx.x] = sh[255];
}

__global__ void scan2_kernel(int* __restrict__ bsum, int nb) {
    __shared__ int sh[512];
    int v = (threadIdx.x < nb) ? bsum[threadIdx.x] : 0;
    sh[threadIdx.x] = v;
    __syncthreads();
    for (int d = 1; d < 512; d <<= 1) {
        int t = (threadIdx.x >= d) ? sh[threadIdx.x - d] : 0;
        __syncthreads();
        sh[threadIdx.x] += t;
        __syncthreads();
    }
    int excl = (threadIdx.x == 0) ? 0 : sh[threadIdx.x - 1];
    if (threadIdx.x < nb) bsum[threadIdx.x] = excl;
}

// finalize starts into cnt (in place) and a second cursor copy for the fill
__global__ void scan3_kernel(int* __restrict__ data, const int* __restrict__ bsum,
                             int* __restrict__ cur, int n) {
    int i = blockIdx.x * blockDim.x + threadIdx.x;
    if (i < n) {
        int v = data[i] + bsum[i >> 12];
        data[i] = v;
        cur[i] = v;
    }
}

// ---------------------------------------------------------------------------
// CSR fill: pos = cur[d]++ (returning atomic); col[pos] = src via atomicExch
// (atomics write payload-only — avoids the 16x partial-line store amplification)
// ---------------------------------------------------------------------------
__global__ void fill_kernel(const int* __restrict__ src, const int* __restrict__ dst,
                            int* __restrict__ cur, unsigned int* __restrict__ col, int E) {
    int e = blockIdx.x * blockDim.x + threadIdx.x;
    if (e < E) {
        int d = dst[e];
        int pos = atomicAdd(&cur[d], 1);
        atomicExch(&col[pos], (unsigned int)src[e]);
    }
}

// ---------------------------------------------------------------------------
// hA[row,:] = dinv[row] * (x[row,:] @ W1)
// ---------------------------------------------------------------------------
__global__ void gemm_kernel(const float* __restrict__ X, const float* __restrict__ W,
                            const float* __restrict__ dinv, float* __restrict__ Y, int n) {
    __shared__ float Wl[FIN * HDIM];
    for (int t = threadIdx.x; t < FIN * HDIM; t += blockDim.x) Wl[t] = W[t];
    __syncthreads();

    int row = blockIdx.x * blockDim.x + threadIdx.x;
    int stride = gridDim.x * blockDim.x;
    for (; row < n; row += stride) {
        float acc[HDIM];
#pragma unroll
        for (int j = 0; j < HDIM; ++j) acc[j] = 0.0f;
        const float* xr = X + (size_t)row * FIN;
#pragma unroll
        for (int k = 0; k < FIN; ++k) {
            float xv = xr[k];
#pragma unroll
            for (int j = 0; j < HDIM; ++j)
                acc[j] = fmaf(xv, Wl[k * HDIM + j], acc[j]);
        }
        float di = dinv[row];
        float4* yo = (float4*)(Y + (size_t)row * HDIM);
        yo[0] = make_float4(di * acc[0], di * acc[1], di * acc[2], di * acc[3]);
        yo[1] = make_float4(di * acc[4], di * acc[5], di * acc[6], di * acc[7]);
        yo[2] = make_float4(di * acc[8], di * acc[9], di * acc[10], di * acc[11]);
        yo[3] = make_float4(di * acc[12], di * acc[13], di * acc[14], di * acc[15]);
    }
}

// ---------------------------------------------------------------------------
// Gather: 4 lanes per node, float4 per lane. hs = dinv-prescaled features.
//   acc4 = hs[i] + sum_{s in N(i)} hs[s]        (register accumulation)
//   r4   = relu(dinv_i * acc4 + bias)
//   FUSE_W2: out[i] = dinv_i * (r @ W2)  via 4-lane float4 shuffles
// cs[i] = CSR start of node i; end = cs[i+1] (or E for last node).
// ---------------------------------------------------------------------------
template <bool FUSE_W2>
__global__ void gather_kernel(const unsigned int* __restrict__ col, const int* __restrict__ cs,
                              const float4* __restrict__ hs4, const float* __restrict__ dinv,
                              const float* __restrict__ bias, const float* __restrict__ W2,
                              float4* __restrict__ out4, int n, int E) {
    __shared__ float4 W2l[HDIM * 4];   // W2l[jj*4+q] = W2[jj][4q..4q+3]
    if constexpr (FUSE_W2) {
        for (int t = threadIdx.x; t < HDIM * 4; t += blockDim.x)
            W2l[t] = ((const float4*)W2)[t];
        __syncthreads();
    }
    int idx = blockIdx.x * blockDim.x + threadIdx.x;
    int i = idx >> 2;
    int q = idx & 3;
    if (i >= n) return;
    int start = cs[i];
    int end = (i + 1 < n) ? cs[i + 1] : E;

    float4 acc = hs4[(size_t)i * 4 + q];   // self-loop term
    int k = start;
    for (; k + 3 < end; k += 4) {
        unsigned int s0 = col[k], s1 = col[k + 1], s2 = col[k + 2], s3 = col[k + 3];
        float4 h0 = hs4[(size_t)s0 * 4 + q];
        float4 h1 = hs4[(size_t)s1 * 4 + q];
        float4 h2 = hs4[(size_t)s2 * 4 + q];
        float4 h3 = hs4[(size_t)s3 * 4 + q];
        acc.x += h0.x + h1.x + h2.x + h3.x;
        acc.y += h0.y + h1.y + h2.y + h3.y;
        acc.z += h0.z + h1.z + h2.z + h3.z;
        acc.w += h0.w + h1.w + h2.w + h3.w;
    }
    for (; k < end; ++k) {
        float4 h = hs4[(size_t)col[k] * 4 + q];
        acc.x += h.x; acc.y += h.y; acc.z += h.z; acc.w += h.w;
    }

    float di = dinv[i];
    float4 b4 = ((const float4*)bias)[q];
    float4 r;
    r.x = fmaxf(fmaf(di, acc.x, b4.x), 0.0f);
    r.y = fmaxf(fmaf(di, acc.y, b4.y), 0.0f);
    r.z = fmaxf(fmaf(di, acc.z, b4.z), 0.0f);
    r.w = fmaxf(fmaf(di, acc.w, b4.w), 0.0f);

    if constexpr (FUSE_W2) {
        int lane = threadIdx.x & 63;
        int base = lane & ~3;             // first lane of this node's 4-lane group
        float4 o = make_float4(0.f, 0.f, 0.f, 0.f);
#pragma unroll
        for (int p = 0; p < 4; ++p) {     // partner lane p holds r for jj = 4p..4p+3
            float rx = __shfl(r.x, base + p, 64);
            float ry = __shfl(r.y, base + p, 64);
            float rz = __shfl(r.z, base + p, 64);
            float rw = __shfl(r.w, base + p, 64);
            float4 w0 = W2l[(p * 4 + 0) * 4 + q];
            float4 w1 = W2l[(p * 4 + 1) * 4 + q];
            float4 w2 = W2l[(p * 4 + 2) * 4 + q];
            float4 w3 = W2l[(p * 4 + 3) * 4 + q];
            o.x = fmaf(rx, w0.x, fmaf(ry, w1.x, fmaf(rz, w2.x, fmaf(rw, w3.x, o.x))));
            o.y = fmaf(rx, w0.y, fmaf(ry, w1.y, fmaf(rz, w2.y, fmaf(rw, w3.y, o.y))));
            o.z = fmaf(rx, w0.z, fmaf(ry, w1.z, fmaf(rz, w2.z, fmaf(rw, w3.z, o.z))));
            o.w = fmaf(rx, w0.w, fmaf(ry, w1.w, fmaf(rz, w2.w, fmaf(rw, w3.w, o.w))));
        }
        out4[(size_t)i * 4 + q] = make_float4(di * o.x, di * o.y, di * o.z, di * o.w);
    } else {
        out4[(size_t)i * 4 + q] = r;
    }
}

extern "C" void kernel_launch(void* const* d_in, const int* in_sizes, int n_in,
                              void* d_out, int out_size, void* d_ws, size_t ws_size,
                              hipStream_t stream) {
    const float* x  = (const float*)d_in[0];   // [n, 54]
    const int*   ei = (const int*)d_in[1];     // [2, E]
    const float* W1 = (const float*)d_in[2];   // [54, 16]
    const float* b1 = (const float*)d_in[3];   // [16]
    const float* W2 = (const float*)d_in[4];   // [16, 16]
    const float* b2 = (const float*)d_in[5];   // [16]
    float* out = (float*)d_out;

    const int E = in_sizes[1] / 2;             // 3,200,000
    const int n = in_sizes[0] / FIN;           // 100,000
    const int* src = ei;
    const int* dst = ei + E;

    char* w = (char*)d_ws;
    float* dinv = (float*)w;                   w += (size_t)n * 4;
    float* hA   = (float*)w;                   w += (size_t)n * HDIM * 4;
    float* hB   = (float*)w;                   w += (size_t)n * HDIM * 4;
    int*   cnt  = (int*)w;                     w += (size_t)n * 4;   // -> CSR starts
    int*   cur  = (int*)w;                     w += (size_t)n * 4;   // fill cursors
    int*   bsum = (int*)w;                     w += 512 * 4;
    unsigned int* col = (unsigned int*)w;      // E u32 (~12.8 MB)

    const int B = 256;
    const int nscan = (n + 4095) >> 12;        // 25 scan blocks

    // --- degree + CSR starts + cursors ---
    hipMemsetAsync(cnt, 0, (size_t)n * 4, stream);
    count_kernel<<<(E + B - 1) / B, B, 0, stream>>>(dst, cnt, E);
    scan1_kernel<<<nscan, 256, 0, stream>>>(cnt, bsum, dinv, n);
    scan2_kernel<<<1, 512, 0, stream>>>(bsum, nscan);
    scan3_kernel<<<(n + B - 1) / B, B, 0, stream>>>(cnt, bsum, cur, n);

    // --- CSR col via atomics (payload-only write traffic) ---
    fill_kernel<<<(E + B - 1) / B, B, 0, stream>>>(src, dst, cur, col, E);

    // --- layer 1 transform (pre-scaled by dinv) ---
    gemm_kernel<<<1024, B, 0, stream>>>(x, W1, dinv, hA, n);

    // --- layer 1 gather + relu + fused @W2 (pre-scaled) -> hB ---
    gather_kernel<true><<<(n * 4 + B - 1) / B, B, 0, stream>>>(
        col, cnt, (const float4*)hA, dinv, b1, W2, (float4*)hB, n, E);

    // --- layer 2 gather + bias + relu -> out ---
    gather_kernel<false><<<(n * 4 + B - 1) / B, B, 0, stream>>>(
        col, cnt, (const float4*)hB, dinv, b2, nullptr, (float4*)out, n, E);
}

// Round 9
// 304.008 us; speedup vs baseline: 4.4869x; 2.0298x over previous
//
#include <hip/hip_runtime.h>

#define HDIM 16
#define FIN 54
#define BSHIFT 7                  // 128 nodes per bucket
#define BNODES (1 << BSHIFT)      // 128
#define NB_BLK 256                // binning blocks == histogram columns
#define CAP 6144                  // LDS stage entries in local_sort (24 KB)

// ---------------------------------------------------------------------------
// pass A1: per-(bucket,block) histogram of dst>>7  (bucket-major layout)
// ---------------------------------------------------------------------------
__global__ void hist_kernel(const int* __restrict__ dst, int* __restrict__ gh,
                            int E, int nb) {
    __shared__ int lh[800];                 // nb = 782 <= 800
    for (int t = threadIdx.x; t < nb; t += blockDim.x) lh[t] = 0;
    __syncthreads();
    int per = (E + NB_BLK - 1) / NB_BLK;
    int s0 = blockIdx.x * per;
    int s1 = min(E, s0 + per);
    for (int e = s0 + threadIdx.x; e < s1; e += blockDim.x)
        atomicAdd(&lh[dst[e] >> BSHIFT], 1);
    __syncthreads();
    for (int t = threadIdx.x; t < nb; t += blockDim.x)
        gh[t * NB_BLK + blockIdx.x] = lh[t];
}

// ---------------------------------------------------------------------------
// generic exclusive scan (in place), 256 threads x 16 = 4096 elems per block
// ---------------------------------------------------------------------------
__global__ void scan1_kernel(int* __restrict__ data, int* __restrict__ bsum, int n) {
    __shared__ int sh[256];
    int off = blockIdx.x * 4096 + threadIdx.x * 16;
    int vals[16];
    int local = 0;
#pragma unroll
    for (int k = 0; k < 16; ++k) {
        int v = (off + k < n) ? data[off + k] : 0;
        vals[k] = v;
        local += v;
    }
    sh[threadIdx.x] = local;
    __syncthreads();
#pragma unroll
    for (int d = 1; d < 256; d <<= 1) {
        int t = (threadIdx.x >= d) ? sh[threadIdx.x - d] : 0;
        __syncthreads();
        sh[threadIdx.x] += t;
        __syncthreads();
    }
    int run = (threadIdx.x == 0) ? 0 : sh[threadIdx.x - 1];
#pragma unroll
    for (int k = 0; k < 16; ++k) {
        if (off + k < n) data[off + k] = run;
        run += vals[k];
    }
    if (threadIdx.x == 0) bsum[blockIdx.x] = sh[255];
}

__global__ void scan2_kernel(int* __restrict__ bsum, int nb) {
    __shared__ int sh[512];
    int v = (threadIdx.x < nb) ? bsum[threadIdx.x] : 0;
    sh[threadIdx.x] = v;
    __syncthreads();
    for (int d = 1; d < 512; d <<= 1) {
        int t = (threadIdx.x >= d) ? sh[threadIdx.x - d] : 0;
        __syncthreads();
        sh[threadIdx.x] += t;
        __syncthreads();
    }
    int excl = (threadIdx.x == 0) ? 0 : sh[threadIdx.x - 1];
    if (threadIdx.x < nb) bsum[threadIdx.x] = excl;
}

__global__ void scan3_kernel(int* __restrict__ data, const int* __restrict__ bsum, int n) {
    int i = blockIdx.x * blockDim.x + threadIdx.x;
    if (i < n) data[i] += bsum[i >> 12];
}

// segstart[b] = bucket start for b in [0,nb); segstart[nb] = E
__global__ void segstart_kernel(const int* __restrict__ gh, int* __restrict__ segstart,
                                int nb, int E) {
    int t = blockIdx.x * blockDim.x + threadIdx.x;
    if (t < nb) segstart[t] = gh[t * NB_BLK];
    if (t == nb) segstart[nb] = E;
}

// ---------------------------------------------------------------------------
// pass A2: place edges into per-(bucket,block) contiguous cells (full-line
// writes). binned[pos] = (src<<7) | dstLow   (17+7 = 24 bits)
// ---------------------------------------------------------------------------
__global__ void fill_binned_kernel(const int* __restrict__ src, const int* __restrict__ dst,
                                   const int* __restrict__ gh,
                                   unsigned int* __restrict__ binned, int E, int nb) {
    __shared__ int lcur[800];
    for (int t = threadIdx.x; t < nb; t += blockDim.x)
        lcur[t] = gh[t * NB_BLK + blockIdx.x];
    __syncthreads();
    int per = (E + NB_BLK - 1) / NB_BLK;
    int s0 = blockIdx.x * per;
    int s1 = min(E, s0 + per);
    for (int e = s0 + threadIdx.x; e < s1; e += blockDim.x) {
        int d = dst[e];
        int b = d >> BSHIFT;
        int pos = atomicAdd(&lcur[b], 1);
        binned[pos] = ((unsigned int)src[e] << BSHIFT) | (unsigned int)(d & (BNODES - 1));
    }
}

// ---------------------------------------------------------------------------
// pass B: per-bucket counting sort to full CSR order via LDS staging.
// Also emits per-node dinv and CSR starts (node lives in exactly one bucket).
// ---------------------------------------------------------------------------
__global__ __launch_bounds__(256)
void local_sort_kernel(const unsigned int* __restrict__ binned,
                       const int* __restrict__ segstart,
                       unsigned int* __restrict__ col, int* __restrict__ cs,
                       float* __restrict__ dinv, int n) {
    __shared__ unsigned int stage[CAP];     // 24 KB
    __shared__ int hist[BNODES], scn[BNODES], cur[BNODES];
    int b = blockIdx.x;
    int s0 = segstart[b], s1 = segstart[b + 1];
    int t = threadIdx.x;

    if (t < BNODES) hist[t] = 0;
    __syncthreads();
    for (int k = s0 + t; k < s1; k += 256)
        atomicAdd(&hist[binned[k] & (BNODES - 1)], 1);
    __syncthreads();
    if (t < BNODES) scn[t] = hist[t];
    __syncthreads();
    for (int d = 1; d < BNODES; d <<= 1) {
        int v = (t < BNODES && t >= d) ? scn[t - d] : 0;
        __syncthreads();
        if (t < BNODES) scn[t] += v;
        __syncthreads();
    }
    if (t < BNODES) {
        int excl = scn[t] - hist[t];        // exclusive scan
        cur[t] = excl;
        int node = (b << BSHIFT) + t;
        if (node < n) {
            cs[node] = s0 + excl;
            dinv[node] = rsqrtf((float)hist[t] + 1.0f);
        }
    }
    __syncthreads();
    for (int k = s0 + t; k < s1; k += 256) {
        unsigned int p = binned[k];
        int pos = atomicAdd(&cur[p & (BNODES - 1)], 1);
        unsigned int sv = p >> BSHIFT;
        if (pos < CAP) stage[pos] = sv;
        else col[s0 + pos] = sv;            // statistically-never overflow path
    }
    __syncthreads();
    int len = s1 - s0;
    if (len > CAP) len = CAP;
    for (int k = t; k < len; k += 256) col[s0 + k] = stage[k];   // coalesced
}

// ---------------------------------------------------------------------------
// hA[row,:] = dinv[row] * (x[row,:] @ W1)
// ---------------------------------------------------------------------------
__global__ void gemm_kernel(const float* __restrict__ X, const float* __restrict__ W,
                            const float* __restrict__ dinv, float* __restrict__ Y, int n) {
    __shared__ float Wl[FIN * HDIM];
    for (int t = threadIdx.x; t < FIN * HDIM; t += blockDim.x) Wl[t] = W[t];
    __syncthreads();

    int row = blockIdx.x * blockDim.x + threadIdx.x;
    int stride = gridDim.x * blockDim.x;
    for (; row < n; row += stride) {
        float acc[HDIM];
#pragma unroll
        for (int j = 0; j < HDIM; ++j) acc[j] = 0.0f;
        const float* xr = X + (size_t)row * FIN;
#pragma unroll
        for (int k = 0; k < FIN; ++k) {
            float xv = xr[k];
#pragma unroll
            for (int j = 0; j < HDIM; ++j)
                acc[j] = fmaf(xv, Wl[k * HDIM + j], acc[j]);
        }
        float di = dinv[row];
        float4* yo = (float4*)(Y + (size_t)row * HDIM);
        yo[0] = make_float4(di * acc[0], di * acc[1], di * acc[2], di * acc[3]);
        yo[1] = make_float4(di * acc[4], di * acc[5], di * acc[6], di * acc[7]);
        yo[2] = make_float4(di * acc[8], di * acc[9], di * acc[10], di * acc[11]);
        yo[3] = make_float4(di * acc[12], di * acc[13], di * acc[14], di * acc[15]);
    }
}

// ---------------------------------------------------------------------------
// Gather: 4 lanes per node, float4 per lane. hs = dinv-prescaled features.
//   acc4 = hs[i] + sum_{s in N(i)} hs[s]
//   r4   = relu(dinv_i * acc4 + bias)
//   FUSE_W2: out[i] = dinv_i * (r @ W2)  via 4-lane float4 shuffles
// ---------------------------------------------------------------------------
template <bool FUSE_W2>
__global__ void gather_kernel(const unsigned int* __restrict__ col, const int* __restrict__ cs,
                              const float4* __restrict__ hs4, const float* __restrict__ dinv,
                              const float* __restrict__ bias, const float* __restrict__ W2,
                              float4* __restrict__ out4, int n, int E) {
    __shared__ float4 W2l[HDIM * 4];   // W2l[jj*4+q] = W2[jj][4q..4q+3]
    if constexpr (FUSE_W2) {
        for (int t = threadIdx.x; t < HDIM * 4; t += blockDim.x)
            W2l[t] = ((const float4*)W2)[t];
        __syncthreads();
    }
    int idx = blockIdx.x * blockDim.x + threadIdx.x;
    int i = idx >> 2;
    int q = idx & 3;
    if (i >= n) return;
    int start = cs[i];
    int end = (i + 1 < n) ? cs[i + 1] : E;

    float4 acc = hs4[(size_t)i * 4 + q];   // self-loop term
    int k = start;
    for (; k + 3 < end; k += 4) {
        unsigned int s0 = col[k], s1 = col[k + 1], s2 = col[k + 2], s3 = col[k + 3];
        float4 h0 = hs4[(size_t)s0 * 4 + q];
        float4 h1 = hs4[(size_t)s1 * 4 + q];
        float4 h2 = hs4[(size_t)s2 * 4 + q];
        float4 h3 = hs4[(size_t)s3 * 4 + q];
        acc.x += h0.x + h1.x + h2.x + h3.x;
        acc.y += h0.y + h1.y + h2.y + h3.y;
        acc.z += h0.z + h1.z + h2.z + h3.z;
        acc.w += h0.w + h1.w + h2.w + h3.w;
    }
    for (; k < end; ++k) {
        float4 h = hs4[(size_t)col[k] * 4 + q];
        acc.x += h.x; acc.y += h.y; acc.z += h.z; acc.w += h.w;
    }

    float di = dinv[i];
    float4 b4 = ((const float4*)bias)[q];
    float4 r;
    r.x = fmaxf(fmaf(di, acc.x, b4.x), 0.0f);
    r.y = fmaxf(fmaf(di, acc.y, b4.y), 0.0f);
    r.z = fmaxf(fmaf(di, acc.z, b4.z), 0.0f);
    r.w = fmaxf(fmaf(di, acc.w, b4.w), 0.0f);

    if constexpr (FUSE_W2) {
        int lane = threadIdx.x & 63;
        int base = lane & ~3;
        float4 o = make_float4(0.f, 0.f, 0.f, 0.f);
#pragma unroll
        for (int p = 0; p < 4; ++p) {
            float rx = __shfl(r.x, base + p, 64);
            float ry = __shfl(r.y, base + p, 64);
            float rz = __shfl(r.z, base + p, 64);
            float rw = __shfl(r.w, base + p, 64);
            float4 w0 = W2l[(p * 4 + 0) * 4 + q];
            float4 w1 = W2l[(p * 4 + 1) * 4 + q];
            float4 w2 = W2l[(p * 4 + 2) * 4 + q];
            float4 w3 = W2l[(p * 4 + 3) * 4 + q];
            o.x = fmaf(rx, w0.x, fmaf(ry, w1.x, fmaf(rz, w2.x, fmaf(rw, w3.x, o.x))));
            o.y = fmaf(rx, w0.y, fmaf(ry, w1.y, fmaf(rz, w2.y, fmaf(rw, w3.y, o.y))));
            o.z = fmaf(rx, w0.z, fmaf(ry, w1.z, fmaf(rz, w2.z, fmaf(rw, w3.z, o.z))));
            o.w = fmaf(rx, w0.w, fmaf(ry, w1.w, fmaf(rz, w2.w, fmaf(rw, w3.w, o.w))));
        }
        out4[(size_t)i * 4 + q] = make_float4(di * o.x, di * o.y, di * o.z, di * o.w);
    } else {
        out4[(size_t)i * 4 + q] = r;
    }
}

extern "C" void kernel_launch(void* const* d_in, const int* in_sizes, int n_in,
                              void* d_out, int out_size, void* d_ws, size_t ws_size,
                              hipStream_t stream) {
    const float* x  = (const float*)d_in[0];   // [n, 54]
    const int*   ei = (const int*)d_in[1];     // [2, E]
    const float* W1 = (const float*)d_in[2];   // [54, 16]
    const float* b1 = (const float*)d_in[3];   // [16]
    const float* W2 = (const float*)d_in[4];   // [16, 16]
    const float* b2 = (const float*)d_in[5];   // [16]
    float* out = (float*)d_out;

    const int E = in_sizes[1] / 2;             // 3,200,000
    const int n = in_sizes[0] / FIN;           // 100,000
    const int* src = ei;
    const int* dst = ei + E;
    const int nb = (n + BNODES - 1) >> BSHIFT; // 782 buckets
    const int M = nb * NB_BLK;                 // 200,192 counters

    char* w = (char*)d_ws;
    float* dinv     = (float*)w;               w += (size_t)n * 4;
    int*   gh       = (int*)w;                 w += (size_t)M * 4;
    int*   bsum     = (int*)w;                 w += 512 * 4;
    int*   segstart = (int*)w;                 w += 1024 * 4;
    int*   cs       = (int*)w;                 w += (size_t)n * 4;
    char*  X        = w;                       // 12.8 MB shared region:
    unsigned int* binned = (unsigned int*)X;   //   build: binned[E]
    float* hA       = (float*)X;               //   later: hA[16n] (binned dead)
    float* hB       = (float*)(X + (size_t)n * HDIM * 4);
    {
        size_t xsz = (size_t)E * 4;
        size_t hsz = (size_t)n * HDIM * 8;
        w = X + (xsz > hsz ? xsz : hsz);
    }
    unsigned int* col = (unsigned int*)w;      // E u32 (12.8 MB)

    const int B = 256;
    const int nscan = (M + 4095) >> 12;        // 49

    // --- build: two-level counting sort -> CSR (col, cs) + dinv ---
    hist_kernel<<<NB_BLK, B, 0, stream>>>(dst, gh, E, nb);
    scan1_kernel<<<nscan, 256, 0, stream>>>(gh, bsum, M);
    scan2_kernel<<<1, 512, 0, stream>>>(bsum, nscan);
    scan3_kernel<<<(M + B - 1) / B, B, 0, stream>>>(gh, bsum, M);
    segstart_kernel<<<(nb + B) / B, B, 0, stream>>>(gh, segstart, nb, E);
    fill_binned_kernel<<<NB_BLK, B, 0, stream>>>(src, dst, gh, binned, E, nb);
    local_sort_kernel<<<nb, B, 0, stream>>>(binned, segstart, col, cs, dinv, n);

    // --- layer 1 transform (pre-scaled by dinv); overwrites dead binned ---
    gemm_kernel<<<1024, B, 0, stream>>>(x, W1, dinv, hA, n);

    // --- layer 1 gather + relu + fused @W2 (pre-scaled) -> hB ---
    gather_kernel<true><<<(n * 4 + B - 1) / B, B, 0, stream>>>(
        col, cs, (const float4*)hA, dinv, b1, W2, (float4*)hB, n, E);

    // --- layer 2 gather + bias + relu -> out ---
    gather_kernel<false><<<(n * 4 + B - 1) / B, B, 0, stream>>>(
        col, cs, (const float4*)hB, dinv, b2, nullptr, (float4*)out, n, E);
}

// Round 10
// 177.191 us; speedup vs baseline: 7.6982x; 1.7157x over previous
//
#include <hip/hip_runtime.h>

#define HDIM 16
#define FIN 54
#define BSHIFT 7                  // 128 nodes per bucket
#define BNODES (1 << BSHIFT)      // 128
#define NB_BLK 256                // binning blocks == histogram columns
#define CAP 6144                  // LDS stage entries in local_sort (24 KB)
#define GTILE 256                 // rows per gemm block
#define GPAD 55                   // padded row stride in LDS (gcd(55,32)=1)

// ---------------------------------------------------------------------------
// pass A1: per-(bucket,block) histogram of dst>>7  (bucket-major layout)
// ---------------------------------------------------------------------------
__global__ void hist_kernel(const int* __restrict__ dst, int* __restrict__ gh,
                            int E, int nb) {
    __shared__ int lh[800];                 // nb = 782 <= 800
    for (int t = threadIdx.x; t < nb; t += blockDim.x) lh[t] = 0;
    __syncthreads();
    int per = (E + NB_BLK - 1) / NB_BLK;
    int s0 = blockIdx.x * per;
    int s1 = min(E, s0 + per);
    for (int e = s0 + threadIdx.x; e < s1; e += blockDim.x)
        atomicAdd(&lh[dst[e] >> BSHIFT], 1);
    __syncthreads();
    for (int t = threadIdx.x; t < nb; t += blockDim.x)
        gh[t * NB_BLK + blockIdx.x] = lh[t];
}

// ---------------------------------------------------------------------------
// generic exclusive scan (in place), 256 threads x 16 = 4096 elems per block
// ---------------------------------------------------------------------------
__global__ void scan1_kernel(int* __restrict__ data, int* __restrict__ bsum, int n) {
    __shared__ int sh[256];
    int off = blockIdx.x * 4096 + threadIdx.x * 16;
    int vals[16];
    int local = 0;
#pragma unroll
    for (int k = 0; k < 16; ++k) {
        int v = (off + k < n) ? data[off + k] : 0;
        vals[k] = v;
        local += v;
    }
    sh[threadIdx.x] = local;
    __syncthreads();
#pragma unroll
    for (int d = 1; d < 256; d <<= 1) {
        int t = (threadIdx.x >= d) ? sh[threadIdx.x - d] : 0;
        __syncthreads();
        sh[threadIdx.x] += t;
        __syncthreads();
    }
    int run = (threadIdx.x == 0) ? 0 : sh[threadIdx.x - 1];
#pragma unroll
    for (int k = 0; k < 16; ++k) {
        if (off + k < n) data[off + k] = run;
        run += vals[k];
    }
    if (threadIdx.x == 0) bsum[blockIdx.x] = sh[255];
}

__global__ void scan2_kernel(int* __restrict__ bsum, int nb) {
    __shared__ int sh[512];
    int v = (threadIdx.x < nb) ? bsum[threadIdx.x] : 0;
    sh[threadIdx.x] = v;
    __syncthreads();
    for (int d = 1; d < 512; d <<= 1) {
        int t = (threadIdx.x >= d) ? sh[threadIdx.x - d] : 0;
        __syncthreads();
        sh[threadIdx.x] += t;
        __syncthreads();
    }
    int excl = (threadIdx.x == 0) ? 0 : sh[threadIdx.x - 1];
    if (threadIdx.x < nb) bsum[threadIdx.x] = excl;
}

__global__ void scan3_kernel(int* __restrict__ data, const int* __restrict__ bsum, int n) {
    int i = blockIdx.x * blockDim.x + threadIdx.x;
    if (i < n) data[i] += bsum[i >> 12];
}

// segstart[b] = bucket start for b in [0,nb); segstart[nb] = E
__global__ void segstart_kernel(const int* __restrict__ gh, int* __restrict__ segstart,
                                int nb, int E) {
    int t = blockIdx.x * blockDim.x + threadIdx.x;
    if (t < nb) segstart[t] = gh[t * NB_BLK];
    if (t == nb) segstart[nb] = E;
}

// ---------------------------------------------------------------------------
// pass A2: place edges into per-(bucket,block) contiguous cells (full-line
// writes). binned[pos] = (src<<7) | dstLow   (17+7 = 24 bits)
// ---------------------------------------------------------------------------
__global__ void fill_binned_kernel(const int* __restrict__ src, const int* __restrict__ dst,
                                   const int* __restrict__ gh,
                                   unsigned int* __restrict__ binned, int E, int nb) {
    __shared__ int lcur[800];
    for (int t = threadIdx.x; t < nb; t += blockDim.x)
        lcur[t] = gh[t * NB_BLK + blockIdx.x];
    __syncthreads();
    int per = (E + NB_BLK - 1) / NB_BLK;
    int s0 = blockIdx.x * per;
    int s1 = min(E, s0 + per);
    for (int e = s0 + threadIdx.x; e < s1; e += blockDim.x) {
        int d = dst[e];
        int b = d >> BSHIFT;
        int pos = atomicAdd(&lcur[b], 1);
        binned[pos] = ((unsigned int)src[e] << BSHIFT) | (unsigned int)(d & (BNODES - 1));
    }
}

// ---------------------------------------------------------------------------
// pass B: per-bucket counting sort to full CSR order via LDS staging.
// Also emits per-node dinv and CSR starts (node lives in exactly one bucket).
// ---------------------------------------------------------------------------
__global__ __launch_bounds__(256)
void local_sort_kernel(const unsigned int* __restrict__ binned,
                       const int* __restrict__ segstart,
                       unsigned int* __restrict__ col, int* __restrict__ cs,
                       float* __restrict__ dinv, int n) {
    __shared__ unsigned int stage[CAP];     // 24 KB
    __shared__ int hist[BNODES], scn[BNODES], cur[BNODES];
    int b = blockIdx.x;
    int s0 = segstart[b], s1 = segstart[b + 1];
    int t = threadIdx.x;

    if (t < BNODES) hist[t] = 0;
    __syncthreads();
    for (int k = s0 + t; k < s1; k += 256)
        atomicAdd(&hist[binned[k] & (BNODES - 1)], 1);
    __syncthreads();
    if (t < BNODES) scn[t] = hist[t];
    __syncthreads();
    for (int d = 1; d < BNODES; d <<= 1) {
        int v = (t < BNODES && t >= d) ? scn[t - d] : 0;
        __syncthreads();
        if (t < BNODES) scn[t] += v;
        __syncthreads();
    }
    if (t < BNODES) {
        int excl = scn[t] - hist[t];        // exclusive scan
        cur[t] = excl;
        int node = (b << BSHIFT) + t;
        if (node < n) {
            cs[node] = s0 + excl;
            dinv[node] = rsqrtf((float)hist[t] + 1.0f);
        }
    }
    __syncthreads();
    for (int k = s0 + t; k < s1; k += 256) {
        unsigned int p = binned[k];
        int pos = atomicAdd(&cur[p & (BNODES - 1)], 1);
        unsigned int sv = p >> BSHIFT;
        if (pos < CAP) stage[pos] = sv;
        else col[s0 + pos] = sv;            // statistically-never overflow path
    }
    __syncthreads();
    int len = s1 - s0;
    if (len > CAP) len = CAP;
    for (int k = t; k < len; k += 256) col[s0 + k] = stage[k];   // coalesced
}

// ---------------------------------------------------------------------------
// hA[row,:] = dinv[row] * (x[row,:] @ W1)
// x tile staged in LDS via coalesced float4 loads (row stride padded to 55)
// ---------------------------------------------------------------------------
__global__ __launch_bounds__(256)
void gemm_kernel(const float* __restrict__ X, const float* __restrict__ W,
                 const float* __restrict__ dinv, float* __restrict__ Y, int n) {
    __shared__ float Wl[FIN * HDIM];       // 3456 B
    __shared__ float xl[GTILE * GPAD];     // 56320 B
    for (int t = threadIdx.x; t < FIN * HDIM; t += blockDim.x) Wl[t] = W[t];

    int base = blockIdx.x * GTILE;
    int nrows = min(GTILE, n - base);
    const float* xb = X + (size_t)base * FIN;
    int tot = nrows * FIN;
    // coalesced float4 stage (xb is 16B-aligned: 256*54*4 % 16 == 0)
    for (int i4 = threadIdx.x; i4 < (tot >> 2); i4 += blockDim.x) {
        float4 v = ((const float4*)xb)[i4];
        int i = i4 << 2;
        int r = i / FIN;
        int c = i - r * FIN;
#pragma unroll
        for (int u = 0; u < 4; ++u) {
            int cc = c + u, rr = r;
            if (cc >= FIN) { cc -= FIN; ++rr; }
            xl[rr * GPAD + cc] = (&v.x)[u];
        }
    }
    for (int i = (tot & ~3) + threadIdx.x; i < tot; i += blockDim.x) {
        int r = i / FIN;
        xl[r * GPAD + (i - r * FIN)] = xb[i];
    }
    __syncthreads();

    int t = threadIdx.x;
    if (t < nrows) {
        int row = base + t;
        const float* xr = &xl[t * GPAD];
        float acc[HDIM];
#pragma unroll
        for (int j = 0; j < HDIM; ++j) acc[j] = 0.0f;
#pragma unroll
        for (int k = 0; k < FIN; ++k) {
            float xv = xr[k];
#pragma unroll
            for (int j = 0; j < HDIM; ++j)
                acc[j] = fmaf(xv, Wl[k * HDIM + j], acc[j]);
        }
        float di = dinv[row];
        float4* yo = (float4*)(Y + (size_t)row * HDIM);
        yo[0] = make_float4(di * acc[0], di * acc[1], di * acc[2], di * acc[3]);
        yo[1] = make_float4(di * acc[4], di * acc[5], di * acc[6], di * acc[7]);
        yo[2] = make_float4(di * acc[8], di * acc[9], di * acc[10], di * acc[11]);
        yo[3] = make_float4(di * acc[12], di * acc[13], di * acc[14], di * acc[15]);
    }
}

// ---------------------------------------------------------------------------
// Gather: 4 lanes per node, float4 per lane. hs = dinv-prescaled features.
//   acc4 = hs[i] + sum_{s in N(i)} hs[s]     (unroll-8 for MLP)
//   r4   = relu(dinv_i * acc4 + bias)
//   FUSE_W2: out[i] = dinv_i * (r @ W2)  via 4-lane float4 shuffles
// ---------------------------------------------------------------------------
template <bool FUSE_W2>
__global__ void gather_kernel(const unsigned int* __restrict__ col, const int* __restrict__ cs,
                              const float4* __restrict__ hs4, const float* __restrict__ dinv,
                              const float* __restrict__ bias, const float* __restrict__ W2,
                              float4* __restrict__ out4, int n, int E) {
    __shared__ float4 W2l[HDIM * 4];   // W2l[jj*4+q] = W2[jj][4q..4q+3]
    if constexpr (FUSE_W2) {
        for (int t = threadIdx.x; t < HDIM * 4; t += blockDim.x)
            W2l[t] = ((const float4*)W2)[t];
        __syncthreads();
    }
    int idx = blockIdx.x * blockDim.x + threadIdx.x;
    int i = idx >> 2;
    int q = idx & 3;
    if (i >= n) return;
    int start = cs[i];
    int end = (i + 1 < n) ? cs[i + 1] : E;

    float4 acc = hs4[(size_t)i * 4 + q];   // self-loop term
    int k = start;
    for (; k + 7 < end; k += 8) {
        unsigned int s[8];
#pragma unroll
        for (int u = 0; u < 8; ++u) s[u] = col[k + u];
        float4 h[8];
#pragma unroll
        for (int u = 0; u < 8; ++u) h[u] = hs4[(size_t)s[u] * 4 + q];
#pragma unroll
        for (int u = 0; u < 8; ++u) {
            acc.x += h[u].x; acc.y += h[u].y; acc.z += h[u].z; acc.w += h[u].w;
        }
    }
    for (; k < end; ++k) {
        float4 h = hs4[(size_t)col[k] * 4 + q];
        acc.x += h.x; acc.y += h.y; acc.z += h.z; acc.w += h.w;
    }

    float di = dinv[i];
    float4 b4 = ((const float4*)bias)[q];
    float4 r;
    r.x = fmaxf(fmaf(di, acc.x, b4.x), 0.0f);
    r.y = fmaxf(fmaf(di, acc.y, b4.y), 0.0f);
    r.z = fmaxf(fmaf(di, acc.z, b4.z), 0.0f);
    r.w = fmaxf(fmaf(di, acc.w, b4.w), 0.0f);

    if constexpr (FUSE_W2) {
        int lane = threadIdx.x & 63;
        int base = lane & ~3;
        float4 o = make_float4(0.f, 0.f, 0.f, 0.f);
#pragma unroll
        for (int p = 0; p < 4; ++p) {
            float rx = __shfl(r.x, base + p, 64);
            float ry = __shfl(r.y, base + p, 64);
            float rz = __shfl(r.z, base + p, 64);
            float rw = __shfl(r.w, base + p, 64);
            float4 w0 = W2l[(p * 4 + 0) * 4 + q];
            float4 w1 = W2l[(p * 4 + 1) * 4 + q];
            float4 w2 = W2l[(p * 4 + 2) * 4 + q];
            float4 w3 = W2l[(p * 4 + 3) * 4 + q];
            o.x = fmaf(rx, w0.x, fmaf(ry, w1.x, fmaf(rz, w2.x, fmaf(rw, w3.x, o.x))));
            o.y = fmaf(rx, w0.y, fmaf(ry, w1.y, fmaf(rz, w2.y, fmaf(rw, w3.y, o.y))));
            o.z = fmaf(rx, w0.z, fmaf(ry, w1.z, fmaf(rz, w2.z, fmaf(rw, w3.z, o.z))));
            o.w = fmaf(rx, w0.w, fmaf(ry, w1.w, fmaf(rz, w2.w, fmaf(rw, w3.w, o.w))));
        }
        out4[(size_t)i * 4 + q] = make_float4(di * o.x, di * o.y, di * o.z, di * o.w);
    } else {
        out4[(size_t)i * 4 + q] = r;
    }
}

extern "C" void kernel_launch(void* const* d_in, const int* in_sizes, int n_in,
                              void* d_out, int out_size, void* d_ws, size_t ws_size,
                              hipStream_t stream) {
    const float* x  = (const float*)d_in[0];   // [n, 54]
    const int*   ei = (const int*)d_in[1];     // [2, E]
    const float* W1 = (const float*)d_in[2];   // [54, 16]
    const float* b1 = (const float*)d_in[3];   // [16]
    const float* W2 = (const float*)d_in[4];   // [16, 16]
    const float* b2 = (const float*)d_in[5];   // [16]
    float* out = (float*)d_out;

    const int E = in_sizes[1] / 2;             // 3,200,000
    const int n = in_sizes[0] / FIN;           // 100,000
    const int* src = ei;
    const int* dst = ei + E;
    const int nb = (n + BNODES - 1) >> BSHIFT; // 782 buckets
    const int M = nb * NB_BLK;                 // 200,192 counters

    char* w = (char*)d_ws;
    float* dinv     = (float*)w;               w += (size_t)n * 4;
    int*   gh       = (int*)w;                 w += (size_t)M * 4;
    int*   bsum     = (int*)w;                 w += 512 * 4;
    int*   segstart = (int*)w;                 w += 1024 * 4;
    int*   cs       = (int*)w;                 w += (size_t)n * 4;
    char*  X        = w;                       // 12.8 MB shared region:
    unsigned int* binned = (unsigned int*)X;   //   build: binned[E]
    float* hA       = (float*)X;               //   later: hA[16n] (binned dead)
    float* hB       = (float*)(X + (size_t)n * HDIM * 4);
    {
        size_t xsz = (size_t)E * 4;
        size_t hsz = (size_t)n * HDIM * 8;
        w = X + (xsz > hsz ? xsz : hsz);
    }
    unsigned int* col = (unsigned int*)w;      // E u32 (12.8 MB)

    const int B = 256;
    const int nscan = (M + 4095) >> 12;        // 49

    // --- build: two-level counting sort -> CSR (col, cs) + dinv ---
    hist_kernel<<<NB_BLK, B, 0, stream>>>(dst, gh, E, nb);
    scan1_kernel<<<nscan, 256, 0, stream>>>(gh, bsum, M);
    scan2_kernel<<<1, 512, 0, stream>>>(bsum, nscan);
    scan3_kernel<<<(M + B - 1) / B, B, 0, stream>>>(gh, bsum, M);
    segstart_kernel<<<(nb + B) / B, B, 0, stream>>>(gh, segstart, nb, E);
    fill_binned_kernel<<<NB_BLK, B, 0, stream>>>(src, dst, gh, binned, E, nb);
    local_sort_kernel<<<nb, B, 0, stream>>>(binned, segstart, col, cs, dinv, n);

    // --- layer 1 transform (pre-scaled by dinv); overwrites dead binned ---
    gemm_kernel<<<(n + GTILE - 1) / GTILE, B, 0, stream>>>(x, W1, dinv, hA, n);

    // --- layer 1 gather + relu + fused @W2 (pre-scaled) -> hB ---
    gather_kernel<true><<<(n * 4 + B - 1) / B, B, 0, stream>>>(
        col, cs, (const float4*)hA, dinv, b1, W2, (float4*)hB, n, E);

    // --- layer 2 gather + bias + relu -> out ---
    gather_kernel<false><<<(n * 4 + B - 1) / B, B, 0, stream>>>(
        col, cs, (const float4*)hB, dinv, b2, nullptr, (float4*)out, n, E);
}

// Round 11
// 151.324 us; speedup vs baseline: 9.0141x; 1.1709x over previous
//
#include <hip/hip_runtime.h>

#define HDIM 16
#define FIN 54
#define BSHIFT 7                  // 128 nodes per bucket
#define BNODES (1 << BSHIFT)      // 128
#define NB_BLK 256                // binning blocks == histogram columns
#define FBT 1024                  // threads in hist/fill blocks
#define LST 512                   // threads in local_sort blocks
#define CAP 6144                  // LDS stage entries in local_sort (24 KB)
#define GTILE 256                 // rows per gemm block
#define GPAD 55                   // padded row stride in LDS (gcd(55,32)=1)

// ---------------------------------------------------------------------------
// pass A1: per-(bucket,block) histogram of dst>>7  (bucket-major layout)
// 1024 threads, unroll-4: many independent loads in flight per wave
// ---------------------------------------------------------------------------
__global__ __launch_bounds__(FBT)
void hist_kernel(const int* __restrict__ dst, int* __restrict__ gh, int E, int nb) {
    __shared__ int lh[800];                 // nb = 782 <= 800
    for (int t = threadIdx.x; t < nb; t += FBT) lh[t] = 0;
    __syncthreads();
    int per = (E + NB_BLK - 1) / NB_BLK;
    int s0 = blockIdx.x * per;
    int s1 = min(E, s0 + per);
    int e = s0 + threadIdx.x;
    for (; e + 3 * FBT < s1; e += 4 * FBT) {
        int d0 = dst[e], d1 = dst[e + FBT], d2 = dst[e + 2 * FBT], d3 = dst[e + 3 * FBT];
        atomicAdd(&lh[d0 >> BSHIFT], 1);
        atomicAdd(&lh[d1 >> BSHIFT], 1);
        atomicAdd(&lh[d2 >> BSHIFT], 1);
        atomicAdd(&lh[d3 >> BSHIFT], 1);
    }
    for (; e < s1; e += FBT) atomicAdd(&lh[dst[e] >> BSHIFT], 1);
    __syncthreads();
    for (int t = threadIdx.x; t < nb; t += FBT)
        gh[t * NB_BLK + blockIdx.x] = lh[t];
}

// ---------------------------------------------------------------------------
// generic exclusive scan (in place), 256 threads x 16 = 4096 elems per block
// ---------------------------------------------------------------------------
__global__ void scan1_kernel(int* __restrict__ data, int* __restrict__ bsum, int n) {
    __shared__ int sh[256];
    int off = blockIdx.x * 4096 + threadIdx.x * 16;
    int vals[16];
    int local = 0;
#pragma unroll
    for (int k = 0; k < 16; ++k) {
        int v = (off + k < n) ? data[off + k] : 0;
        vals[k] = v;
        local += v;
    }
    sh[threadIdx.x] = local;
    __syncthreads();
#pragma unroll
    for (int d = 1; d < 256; d <<= 1) {
        int t = (threadIdx.x >= d) ? sh[threadIdx.x - d] : 0;
        __syncthreads();
        sh[threadIdx.x] += t;
        __syncthreads();
    }
    int run = (threadIdx.x == 0) ? 0 : sh[threadIdx.x - 1];
#pragma unroll
    for (int k = 0; k < 16; ++k) {
        if (off + k < n) data[off + k] = run;
        run += vals[k];
    }
    if (threadIdx.x == 0) bsum[blockIdx.x] = sh[255];
}

__global__ void scan2_kernel(int* __restrict__ bsum, int nb) {
    __shared__ int sh[512];
    int v = (threadIdx.x < nb) ? bsum[threadIdx.x] : 0;
    sh[threadIdx.x] = v;
    __syncthreads();
    for (int d = 1; d < 512; d <<= 1) {
        int t = (threadIdx.x >= d) ? sh[threadIdx.x - d] : 0;
        __syncthreads();
        sh[threadIdx.x] += t;
        __syncthreads();
    }
    int excl = (threadIdx.x == 0) ? 0 : sh[threadIdx.x - 1];
    if (threadIdx.x < nb) bsum[threadIdx.x] = excl;
}

// scan finalize + fused segstart extraction (bucket start = gh[b*NB_BLK])
__global__ void scan3_kernel(int* __restrict__ data, const int* __restrict__ bsum,
                             int* __restrict__ segstart, int nb, int E, int M) {
    int i = blockIdx.x * blockDim.x + threadIdx.x;
    if (i < M) {
        int v = data[i] + bsum[i >> 12];
        data[i] = v;
        if ((i & (NB_BLK - 1)) == 0) segstart[i / NB_BLK] = v;
    }
    if (i == 0) segstart[nb] = E;
}

// ---------------------------------------------------------------------------
// pass A2: place edges into per-(bucket,block) contiguous cells (~one 64B
// line each). binned[pos] = (src<<7) | dstLow.  1024 threads, unroll-4.
// ---------------------------------------------------------------------------
__global__ __launch_bounds__(FBT)
void fill_binned_kernel(const int* __restrict__ src, const int* __restrict__ dst,
                        const int* __restrict__ gh,
                        unsigned int* __restrict__ binned, int E, int nb) {
    __shared__ int lcur[800];
    for (int t = threadIdx.x; t < nb; t += FBT)
        lcur[t] = gh[t * NB_BLK + blockIdx.x];
    __syncthreads();
    int per = (E + NB_BLK - 1) / NB_BLK;
    int s0 = blockIdx.x * per;
    int s1 = min(E, s0 + per);
    int e = s0 + threadIdx.x;
    for (; e + 3 * FBT < s1; e += 4 * FBT) {
        int d0 = dst[e], d1 = dst[e + FBT], d2 = dst[e + 2 * FBT], d3 = dst[e + 3 * FBT];
        int v0 = src[e], v1 = src[e + FBT], v2 = src[e + 2 * FBT], v3 = src[e + 3 * FBT];
        int p0 = atomicAdd(&lcur[d0 >> BSHIFT], 1);
        int p1 = atomicAdd(&lcur[d1 >> BSHIFT], 1);
        int p2 = atomicAdd(&lcur[d2 >> BSHIFT], 1);
        int p3 = atomicAdd(&lcur[d3 >> BSHIFT], 1);
        binned[p0] = ((unsigned int)v0 << BSHIFT) | (unsigned int)(d0 & (BNODES - 1));
        binned[p1] = ((unsigned int)v1 << BSHIFT) | (unsigned int)(d1 & (BNODES - 1));
        binned[p2] = ((unsigned int)v2 << BSHIFT) | (unsigned int)(d2 & (BNODES - 1));
        binned[p3] = ((unsigned int)v3 << BSHIFT) | (unsigned int)(d3 & (BNODES - 1));
    }
    for (; e < s1; e += FBT) {
        int d = dst[e];
        int pos = atomicAdd(&lcur[d >> BSHIFT], 1);
        binned[pos] = ((unsigned int)src[e] << BSHIFT) | (unsigned int)(d & (BNODES - 1));
    }
}

// ---------------------------------------------------------------------------
// pass B: per-bucket counting sort to full CSR order via LDS staging.
// Also emits per-node dinv and CSR starts.
// ---------------------------------------------------------------------------
__global__ __launch_bounds__(LST)
void local_sort_kernel(const unsigned int* __restrict__ binned,
                       const int* __restrict__ segstart,
                       unsigned int* __restrict__ col, int* __restrict__ cs,
                       float* __restrict__ dinv, int n) {
    __shared__ unsigned int stage[CAP];     // 24 KB
    __shared__ int hist[BNODES], scn[BNODES], cur[BNODES];
    int b = blockIdx.x;
    int s0 = segstart[b], s1 = segstart[b + 1];
    int t = threadIdx.x;

    if (t < BNODES) hist[t] = 0;
    __syncthreads();
    for (int k = s0 + t; k < s1; k += LST)
        atomicAdd(&hist[binned[k] & (BNODES - 1)], 1);
    __syncthreads();
    if (t < BNODES) scn[t] = hist[t];
    __syncthreads();
    for (int d = 1; d < BNODES; d <<= 1) {
        int v = (t < BNODES && t >= d) ? scn[t - d] : 0;
        __syncthreads();
        if (t < BNODES) scn[t] += v;
        __syncthreads();
    }
    if (t < BNODES) {
        int excl = scn[t] - hist[t];        // exclusive scan
        cur[t] = excl;
        int node = (b << BSHIFT) + t;
        if (node < n) {
            cs[node] = s0 + excl;
            dinv[node] = rsqrtf((float)hist[t] + 1.0f);
        }
    }
    __syncthreads();
    for (int k = s0 + t; k < s1; k += LST) {
        unsigned int p = binned[k];
        int pos = atomicAdd(&cur[p & (BNODES - 1)], 1);
        unsigned int sv = p >> BSHIFT;
        if (pos < CAP) stage[pos] = sv;
        else col[s0 + pos] = sv;            // statistically-never overflow path
    }
    __syncthreads();
    int len = s1 - s0;
    if (len > CAP) len = CAP;
    for (int k = t; k < len; k += LST) col[s0 + k] = stage[k];   // coalesced
}

// ---------------------------------------------------------------------------
// hA[row,:] = dinv[row] * (x[row,:] @ W1), x tile staged in LDS (coalesced)
// ---------------------------------------------------------------------------
__global__ __launch_bounds__(256)
void gemm_kernel(const float* __restrict__ X, const float* __restrict__ W,
                 const float* __restrict__ dinv, float* __restrict__ Y, int n) {
    __shared__ float Wl[FIN * HDIM];       // 3456 B
    __shared__ float xl[GTILE * GPAD];     // 56320 B
    for (int t = threadIdx.x; t < FIN * HDIM; t += blockDim.x) Wl[t] = W[t];

    int base = blockIdx.x * GTILE;
    int nrows = min(GTILE, n - base);
    const float* xb = X + (size_t)base * FIN;
    int tot = nrows * FIN;
    for (int i4 = threadIdx.x; i4 < (tot >> 2); i4 += blockDim.x) {
        float4 v = ((const float4*)xb)[i4];
        int i = i4 << 2;
        int r = i / FIN;
        int c = i - r * FIN;
#pragma unroll
        for (int u = 0; u < 4; ++u) {
            int cc = c + u, rr = r;
            if (cc >= FIN) { cc -= FIN; ++rr; }
            xl[rr * GPAD + cc] = (&v.x)[u];
        }
    }
    for (int i = (tot & ~3) + threadIdx.x; i < tot; i += blockDim.x) {
        int r = i / FIN;
        xl[r * GPAD + (i - r * FIN)] = xb[i];
    }
    __syncthreads();

    int t = threadIdx.x;
    if (t < nrows) {
        int row = base + t;
        const float* xr = &xl[t * GPAD];
        float acc[HDIM];
#pragma unroll
        for (int j = 0; j < HDIM; ++j) acc[j] = 0.0f;
#pragma unroll
        for (int k = 0; k < FIN; ++k) {
            float xv = xr[k];
#pragma unroll
            for (int j = 0; j < HDIM; ++j)
                acc[j] = fmaf(xv, Wl[k * HDIM + j], acc[j]);
        }
        float di = dinv[row];
        float4* yo = (float4*)(Y + (size_t)row * HDIM);
        yo[0] = make_float4(di * acc[0], di * acc[1], di * acc[2], di * acc[3]);
        yo[1] = make_float4(di * acc[4], di * acc[5], di * acc[6], di * acc[7]);
        yo[2] = make_float4(di * acc[8], di * acc[9], di * acc[10], di * acc[11]);
        yo[3] = make_float4(di * acc[12], di * acc[13], di * acc[14], di * acc[15]);
    }
}

// ---------------------------------------------------------------------------
// Gather: 4 lanes per node, float4 per lane. hs = dinv-prescaled features.
// ---------------------------------------------------------------------------
template <bool FUSE_W2>
__global__ void gather_kernel(const unsigned int* __restrict__ col, const int* __restrict__ cs,
                              const float4* __restrict__ hs4, const float* __restrict__ dinv,
                              const float* __restrict__ bias, const float* __restrict__ W2,
                              float4* __restrict__ out4, int n, int E) {
    __shared__ float4 W2l[HDIM * 4];   // W2l[jj*4+q] = W2[jj][4q..4q+3]
    if constexpr (FUSE_W2) {
        for (int t = threadIdx.x; t < HDIM * 4; t += blockDim.x)
            W2l[t] = ((const float4*)W2)[t];
        __syncthreads();
    }
    int idx = blockIdx.x * blockDim.x + threadIdx.x;
    int i = idx >> 2;
    int q = idx & 3;
    if (i >= n) return;
    int start = cs[i];
    int end = (i + 1 < n) ? cs[i + 1] : E;

    float4 acc = hs4[(size_t)i * 4 + q];   // self-loop term
    int k = start;
    for (; k + 7 < end; k += 8) {
        unsigned int s[8];
#pragma unroll
        for (int u = 0; u < 8; ++u) s[u] = col[k + u];
        float4 h[8];
#pragma unroll
        for (int u = 0; u < 8; ++u) h[u] = hs4[(size_t)s[u] * 4 + q];
#pragma unroll
        for (int u = 0; u < 8; ++u) {
            acc.x += h[u].x; acc.y += h[u].y; acc.z += h[u].z; acc.w += h[u].w;
        }
    }
    for (; k < end; ++k) {
        float4 h = hs4[(size_t)col[k] * 4 + q];
        acc.x += h.x; acc.y += h.y; acc.z += h.z; acc.w += h.w;
    }

    float di = dinv[i];
    float4 b4 = ((const float4*)bias)[q];
    float4 r;
    r.x = fmaxf(fmaf(di, acc.x, b4.x), 0.0f);
    r.y = fmaxf(fmaf(di, acc.y, b4.y), 0.0f);
    r.z = fmaxf(fmaf(di, acc.z, b4.z), 0.0f);
    r.w = fmaxf(fmaf(di, acc.w, b4.w), 0.0f);

    if constexpr (FUSE_W2) {
        int lane = threadIdx.x & 63;
        int base = lane & ~3;
        float4 o = make_float4(0.f, 0.f, 0.f, 0.f);
#pragma unroll
        for (int p = 0; p < 4; ++p) {
            float rx = __shfl(r.x, base + p, 64);
            float ry = __shfl(r.y, base + p, 64);
            float rz = __shfl(r.z, base + p, 64);
            float rw = __shfl(r.w, base + p, 64);
            float4 w0 = W2l[(p * 4 + 0) * 4 + q];
            float4 w1 = W2l[(p * 4 + 1) * 4 + q];
            float4 w2 = W2l[(p * 4 + 2) * 4 + q];
            float4 w3 = W2l[(p * 4 + 3) * 4 + q];
            o.x = fmaf(rx, w0.x, fmaf(ry, w1.x, fmaf(rz, w2.x, fmaf(rw, w3.x, o.x))));
            o.y = fmaf(rx, w0.y, fmaf(ry, w1.y, fmaf(rz, w2.y, fmaf(rw, w3.y, o.y))));
            o.z = fmaf(rx, w0.z, fmaf(ry, w1.z, fmaf(rz, w2.z, fmaf(rw, w3.z, o.z))));
            o.w = fmaf(rx, w0.w, fmaf(ry, w1.w, fmaf(rz, w2.w, fmaf(rw, w3.w, o.w))));
        }
        out4[(size_t)i * 4 + q] = make_float4(di * o.x, di * o.y, di * o.z, di * o.w);
    } else {
        out4[(size_t)i * 4 + q] = r;
    }
}

extern "C" void kernel_launch(void* const* d_in, const int* in_sizes, int n_in,
                              void* d_out, int out_size, void* d_ws, size_t ws_size,
                              hipStream_t stream) {
    const float* x  = (const float*)d_in[0];   // [n, 54]
    const int*   ei = (const int*)d_in[1];     // [2, E]
    const float* W1 = (const float*)d_in[2];   // [54, 16]
    const float* b1 = (const float*)d_in[3];   // [16]
    const float* W2 = (const float*)d_in[4];   // [16, 16]
    const float* b2 = (const float*)d_in[5];   // [16]
    float* out = (float*)d_out;

    const int E = in_sizes[1] / 2;             // 3,200,000
    const int n = in_sizes[0] / FIN;           // 100,000
    const int* src = ei;
    const int* dst = ei + E;
    const int nb = (n + BNODES - 1) >> BSHIFT; // 782 buckets
    const int M = nb * NB_BLK;                 // 200,192 counters

    char* w = (char*)d_ws;
    float* dinv     = (float*)w;               w += (size_t)n * 4;
    int*   gh       = (int*)w;                 w += (size_t)M * 4;
    int*   bsum     = (int*)w;                 w += 512 * 4;
    int*   segstart = (int*)w;                 w += 1024 * 4;
    int*   cs       = (int*)w;                 w += (size_t)n * 4;
    char*  X        = w;                       // 12.8 MB shared region:
    unsigned int* binned = (unsigned int*)X;   //   build: binned[E]
    float* hA       = (float*)X;               //   later: hA[16n] (binned dead)
    float* hB       = (float*)(X + (size_t)n * HDIM * 4);
    {
        size_t xsz = (size_t)E * 4;
        size_t hsz = (size_t)n * HDIM * 8;
        w = X + (xsz > hsz ? xsz : hsz);
    }
    unsigned int* col = (unsigned int*)w;      // E u32 (12.8 MB)

    const int B = 256;
    const int nscan = (M + 4095) >> 12;        // 49

    // --- build: two-level counting sort -> CSR (col, cs) + dinv ---
    hist_kernel<<<NB_BLK, FBT, 0, stream>>>(dst, gh, E, nb);
    scan1_kernel<<<nscan, 256, 0, stream>>>(gh, bsum, M);
    scan2_kernel<<<1, 512, 0, stream>>>(bsum, nscan);
    scan3_kernel<<<(M + B - 1) / B, B, 0, stream>>>(gh, bsum, segstart, nb, E, M);
    fill_binned_kernel<<<NB_BLK, FBT, 0, stream>>>(src, dst, gh, binned, E, nb);
    local_sort_kernel<<<nb, LST, 0, stream>>>(binned, segstart, col, cs, dinv, n);

    // --- layer 1 transform (pre-scaled by dinv); overwrites dead binned ---
    gemm_kernel<<<(n + GTILE - 1) / GTILE, B, 0, stream>>>(x, W1, dinv, hA, n);

    // --- layer 1 gather + relu + fused @W2 (pre-scaled) -> hB ---
    gather_kernel<true><<<(n * 4 + B - 1) / B, B, 0, stream>>>(
        col, cs, (const float4*)hA, dinv, b1, W2, (float4*)hB, n, E);

    // --- layer 2 gather + bias + relu -> out ---
    gather_kernel<false><<<(n * 4 + B - 1) / B, B, 0, stream>>>(
        col, cs, (const float4*)hB, dinv, b2, nullptr, (float4*)out, n, E);
}

// Round 12
// 126.411 us; speedup vs baseline: 10.7905x; 1.1971x over previous
//
#include <hip/hip_runtime.h>
#include <hip/hip_fp16.h>

#define HDIM 16
#define FIN 54
#define BSHIFT 7                  // 128 nodes per bucket
#define BNODES (1 << BSHIFT)      // 128
#define NB_BLK 256                // binning blocks == histogram columns
#define FBT 1024                  // threads in hist/fill blocks
#define LST 512                   // threads in local_sort blocks
#define CAP 6144                  // LDS stage entries in local_sort (24 KB)
#define GTILE 256                 // rows per gemm block
#define GPAD 55                   // padded row stride in LDS (gcd(55,32)=1)

// ---------------------------------------------------------------------------
// pass A1: per-(bucket,block) histogram of dst>>7, int4-vectorized loads
// ---------------------------------------------------------------------------
__global__ __launch_bounds__(FBT)
void hist_kernel(const int* __restrict__ dst, int* __restrict__ gh, int E, int nb) {
    __shared__ int lh[800];                 // nb = 782 <= 800
    for (int t = threadIdx.x; t < nb; t += FBT) lh[t] = 0;
    __syncthreads();
    int per = (((E + NB_BLK - 1) / NB_BLK) + 3) & ~3;
    int s0 = blockIdx.x * per;              // multiple of 4
    int s1 = min(E, s0 + per);
    int idx = s0 + (threadIdx.x << 2);
    for (; idx + 3 < s1; idx += (FBT << 2)) {
        int4 d4 = *(const int4*)&dst[idx];
        atomicAdd(&lh[d4.x >> BSHIFT], 1);
        atomicAdd(&lh[d4.y >> BSHIFT], 1);
        atomicAdd(&lh[d4.z >> BSHIFT], 1);
        atomicAdd(&lh[d4.w >> BSHIFT], 1);
    }
    if (idx < s1) {
        int stop = min(idx + 4, s1);
        for (int e = idx; e < stop; ++e) atomicAdd(&lh[dst[e] >> BSHIFT], 1);
    }
    __syncthreads();
    for (int t = threadIdx.x; t < nb; t += FBT)
        gh[t * NB_BLK + blockIdx.x] = lh[t];
}

// ---------------------------------------------------------------------------
// generic exclusive scan (in place), 256 threads x 16 = 4096 elems per block
// ---------------------------------------------------------------------------
__global__ void scan1_kernel(int* __restrict__ data, int* __restrict__ bsum, int n) {
    __shared__ int sh[256];
    int off = blockIdx.x * 4096 + threadIdx.x * 16;
    int vals[16];
    int local = 0;
#pragma unroll
    for (int k = 0; k < 16; ++k) {
        int v = (off + k < n) ? data[off + k] : 0;
        vals[k] = v;
        local += v;
    }
    sh[threadIdx.x] = local;
    __syncthreads();
#pragma unroll
    for (int d = 1; d < 256; d <<= 1) {
        int t = (threadIdx.x >= d) ? sh[threadIdx.x - d] : 0;
        __syncthreads();
        sh[threadIdx.x] += t;
        __syncthreads();
    }
    int run = (threadIdx.x == 0) ? 0 : sh[threadIdx.x - 1];
#pragma unroll
    for (int k = 0; k < 16; ++k) {
        if (off + k < n) data[off + k] = run;
        run += vals[k];
    }
    if (threadIdx.x == 0) bsum[blockIdx.x] = sh[255];
}

__global__ void scan2_kernel(int* __restrict__ bsum, int nb) {
    __shared__ int sh[512];
    int v = (threadIdx.x < nb) ? bsum[threadIdx.x] : 0;
    sh[threadIdx.x] = v;
    __syncthreads();
    for (int d = 1; d < 512; d <<= 1) {
        int t = (threadIdx.x >= d) ? sh[threadIdx.x - d] : 0;
        __syncthreads();
        sh[threadIdx.x] += t;
        __syncthreads();
    }
    int excl = (threadIdx.x == 0) ? 0 : sh[threadIdx.x - 1];
    if (threadIdx.x < nb) bsum[threadIdx.x] = excl;
}

// scan finalize + fused segstart extraction (bucket start = gh[b*NB_BLK])
__global__ void scan3_kernel(int* __restrict__ data, const int* __restrict__ bsum,
                             int* __restrict__ segstart, int nb, int E, int M) {
    int i = blockIdx.x * blockDim.x + threadIdx.x;
    if (i < M) {
        int v = data[i] + bsum[i >> 12];
        data[i] = v;
        if ((i & (NB_BLK - 1)) == 0) segstart[i / NB_BLK] = v;
    }
    if (i == 0) segstart[nb] = E;
}

// ---------------------------------------------------------------------------
// pass A2: place edges into per-(bucket,block) contiguous cells.
// binned[pos] = (src<<7) | dstLow.  int4-vectorized input loads.
// ---------------------------------------------------------------------------
__global__ __launch_bounds__(FBT)
void fill_binned_kernel(const int* __restrict__ src, const int* __restrict__ dst,
                        const int* __restrict__ gh,
                        unsigned int* __restrict__ binned, int E, int nb) {
    __shared__ int lcur[800];
    for (int t = threadIdx.x; t < nb; t += FBT)
        lcur[t] = gh[t * NB_BLK + blockIdx.x];
    __syncthreads();
    int per = (((E + NB_BLK - 1) / NB_BLK) + 3) & ~3;
    int s0 = blockIdx.x * per;
    int s1 = min(E, s0 + per);
    int idx = s0 + (threadIdx.x << 2);
    for (; idx + 3 < s1; idx += (FBT << 2)) {
        int4 d4 = *(const int4*)&dst[idx];
        int4 v4 = *(const int4*)&src[idx];
        int p0 = atomicAdd(&lcur[d4.x >> BSHIFT], 1);
        int p1 = atomicAdd(&lcur[d4.y >> BSHIFT], 1);
        int p2 = atomicAdd(&lcur[d4.z >> BSHIFT], 1);
        int p3 = atomicAdd(&lcur[d4.w >> BSHIFT], 1);
        binned[p0] = ((unsigned int)v4.x << BSHIFT) | (unsigned int)(d4.x & (BNODES - 1));
        binned[p1] = ((unsigned int)v4.y << BSHIFT) | (unsigned int)(d4.y & (BNODES - 1));
        binned[p2] = ((unsigned int)v4.z << BSHIFT) | (unsigned int)(d4.z & (BNODES - 1));
        binned[p3] = ((unsigned int)v4.w << BSHIFT) | (unsigned int)(d4.w & (BNODES - 1));
    }
    if (idx < s1) {
        int stop = min(idx + 4, s1);
        for (int e = idx; e < stop; ++e) {
            int d = dst[e];
            int pos = atomicAdd(&lcur[d >> BSHIFT], 1);
            binned[pos] = ((unsigned int)src[e] << BSHIFT) | (unsigned int)(d & (BNODES - 1));
        }
    }
}

// ---------------------------------------------------------------------------
// pass B: per-bucket counting sort to full CSR order via LDS staging.
// Also emits per-node dinv and CSR starts.
// ---------------------------------------------------------------------------
__global__ __launch_bounds__(LST)
void local_sort_kernel(const unsigned int* __restrict__ binned,
                       const int* __restrict__ segstart,
                       unsigned int* __restrict__ col, int* __restrict__ cs,
                       float* __restrict__ dinv, int n) {
    __shared__ unsigned int stage[CAP];     // 24 KB
    __shared__ int hist[BNODES], scn[BNODES], cur[BNODES];
    int b = blockIdx.x;
    int s0 = segstart[b], s1 = segstart[b + 1];
    int t = threadIdx.x;

    if (t < BNODES) hist[t] = 0;
    __syncthreads();
    for (int k = s0 + t; k < s1; k += LST)
        atomicAdd(&hist[binned[k] & (BNODES - 1)], 1);
    __syncthreads();
    if (t < BNODES) scn[t] = hist[t];
    __syncthreads();
    for (int d = 1; d < BNODES; d <<= 1) {
        int v = (t < BNODES && t >= d) ? scn[t - d] : 0;
        __syncthreads();
        if (t < BNODES) scn[t] += v;
        __syncthreads();
    }
    if (t < BNODES) {
        int excl = scn[t] - hist[t];        // exclusive scan
        cur[t] = excl;
        int node = (b << BSHIFT) + t;
        if (node < n) {
            cs[node] = s0 + excl;
            dinv[node] = rsqrtf((float)hist[t] + 1.0f);
        }
    }
    __syncthreads();
    for (int k = s0 + t; k < s1; k += LST) {
        unsigned int p = binned[k];
        int pos = atomicAdd(&cur[p & (BNODES - 1)], 1);
        unsigned int sv = p >> BSHIFT;
        if (pos < CAP) stage[pos] = sv;
        else col[s0 + pos] = sv;            // statistically-never overflow path
    }
    __syncthreads();
    int len = s1 - s0;
    if (len > CAP) len = CAP;
    for (int k = t; k < len; k += LST) col[s0 + k] = stage[k];   // coalesced
}

// ---------------------------------------------------------------------------
// hA[row,:] = fp16( dinv[row] * (x[row,:] @ W1) ), x staged in LDS coalesced
// ---------------------------------------------------------------------------
__global__ __launch_bounds__(256)
void gemm_kernel(const float* __restrict__ X, const float* __restrict__ W,
                 const float* __restrict__ dinv, __half* __restrict__ Yh, int n) {
    __shared__ float Wl[FIN * HDIM];       // 3456 B
    __shared__ float xl[GTILE * GPAD];     // 56320 B
    for (int t = threadIdx.x; t < FIN * HDIM; t += blockDim.x) Wl[t] = W[t];

    int base = blockIdx.x * GTILE;
    int nrows = min(GTILE, n - base);
    const float* xb = X + (size_t)base * FIN;
    int tot = nrows * FIN;
    for (int i4 = threadIdx.x; i4 < (tot >> 2); i4 += blockDim.x) {
        float4 v = ((const float4*)xb)[i4];
        int i = i4 << 2;
        int r = i / FIN;
        int c = i - r * FIN;
#pragma unroll
        for (int u = 0; u < 4; ++u) {
            int cc = c + u, rr = r;
            if (cc >= FIN) { cc -= FIN; ++rr; }
            xl[rr * GPAD + cc] = (&v.x)[u];
        }
    }
    for (int i = (tot & ~3) + threadIdx.x; i < tot; i += blockDim.x) {
        int r = i / FIN;
        xl[r * GPAD + (i - r * FIN)] = xb[i];
    }
    __syncthreads();

    int t = threadIdx.x;
    if (t < nrows) {
        int row = base + t;
        const float* xr = &xl[t * GPAD];
        float acc[HDIM];
#pragma unroll
        for (int j = 0; j < HDIM; ++j) acc[j] = 0.0f;
#pragma unroll
        for (int k = 0; k < FIN; ++k) {
            float xv = xr[k];
#pragma unroll
            for (int j = 0; j < HDIM; ++j)
                acc[j] = fmaf(xv, Wl[k * HDIM + j], acc[j]);
        }
        float di = dinv[row];
        __half2 hh[8];
#pragma unroll
        for (int j = 0; j < 8; ++j)
            hh[j] = __floats2half2_rn(di * acc[2 * j], di * acc[2 * j + 1]);
        uint4* yo = (uint4*)(Yh + ((size_t)row << 4));
        yo[0] = *(uint4*)&hh[0];
        yo[1] = *(uint4*)&hh[4];
    }
}

// ---------------------------------------------------------------------------
// Gather: 4 lanes per node; hs in fp16 (32 B/node -> 3.2 MB, L2-resident).
//   acc4 = hs[i] + sum_{s in N(i)} hs[s]   (f32 accumulation, unroll-8)
//   r4   = relu(dinv_i * acc4 + bias)
//   FUSE_W2: outh[i] = fp16(dinv_i * (r @ W2));  else out4[i] = r (f32)
// ---------------------------------------------------------------------------
__device__ __forceinline__ float4 ld_h4(const __half* __restrict__ hsh,
                                        unsigned int node, int q) {
    const __half2* p = (const __half2*)(hsh + ((size_t)node << 4) + (q << 2));
    float2 fa = __half22float2(p[0]);
    float2 fb = __half22float2(p[1]);
    return make_float4(fa.x, fa.y, fb.x, fb.y);
}

template <bool FUSE_W2>
__global__ void gather_kernel(const unsigned int* __restrict__ col, const int* __restrict__ cs,
                              const __half* __restrict__ hsh, const float* __restrict__ dinv,
                              const float* __restrict__ bias, const float* __restrict__ W2,
                              __half* __restrict__ outh, float4* __restrict__ out4,
                              int n, int E) {
    __shared__ float4 W2l[HDIM * 4];   // W2l[jj*4+q] = W2[jj][4q..4q+3]
    if constexpr (FUSE_W2) {
        for (int t = threadIdx.x; t < HDIM * 4; t += blockDim.x)
            W2l[t] = ((const float4*)W2)[t];
        __syncthreads();
    }
    int idx = blockIdx.x * blockDim.x + threadIdx.x;
    int i = idx >> 2;
    int q = idx & 3;
    if (i >= n) return;
    int start = cs[i];
    int end = (i + 1 < n) ? cs[i + 1] : E;

    float4 acc = ld_h4(hsh, (unsigned int)i, q);   // self-loop term
    int k = start;
    for (; k + 7 < end; k += 8) {
        unsigned int s[8];
#pragma unroll
        for (int u = 0; u < 8; ++u) s[u] = col[k + u];
        float4 h[8];
#pragma unroll
        for (int u = 0; u < 8; ++u) h[u] = ld_h4(hsh, s[u], q);
#pragma unroll
        for (int u = 0; u < 8; ++u) {
            acc.x += h[u].x; acc.y += h[u].y; acc.z += h[u].z; acc.w += h[u].w;
        }
    }
    for (; k < end; ++k) {
        float4 h = ld_h4(hsh, col[k], q);
        acc.x += h.x; acc.y += h.y; acc.z += h.z; acc.w += h.w;
    }

    float di = dinv[i];
    float4 b4 = ((const float4*)bias)[q];
    float4 r;
    r.x = fmaxf(fmaf(di, acc.x, b4.x), 0.0f);
    r.y = fmaxf(fmaf(di, acc.y, b4.y), 0.0f);
    r.z = fmaxf(fmaf(di, acc.z, b4.z), 0.0f);
    r.w = fmaxf(fmaf(di, acc.w, b4.w), 0.0f);

    if constexpr (FUSE_W2) {
        int lane = threadIdx.x & 63;
        int base = lane & ~3;
        float4 o = make_float4(0.f, 0.f, 0.f, 0.f);
#pragma unroll
        for (int p = 0; p < 4; ++p) {
            float rx = __shfl(r.x, base + p, 64);
            float ry = __shfl(r.y, base + p, 64);
            float rz = __shfl(r.z, base + p, 64);
            float rw = __shfl(r.w, base + p, 64);
            float4 w0 = W2l[(p * 4 + 0) * 4 + q];
            float4 w1 = W2l[(p * 4 + 1) * 4 + q];
            float4 w2 = W2l[(p * 4 + 2) * 4 + q];
            float4 w3 = W2l[(p * 4 + 3) * 4 + q];
            o.x = fmaf(rx, w0.x, fmaf(ry, w1.x, fmaf(rz, w2.x, fmaf(rw, w3.x, o.x))));
            o.y = fmaf(rx, w0.y, fmaf(ry, w1.y, fmaf(rz, w2.y, fmaf(rw, w3.y, o.y))));
            o.z = fmaf(rx, w0.z, fmaf(ry, w1.z, fmaf(rz, w2.z, fmaf(rw, w3.z, o.z))));
            o.w = fmaf(rx, w0.w, fmaf(ry, w1.w, fmaf(rz, w2.w, fmaf(rw, w3.w, o.w))));
        }
        __half2 o01 = __floats2half2_rn(di * o.x, di * o.y);
        __half2 o23 = __floats2half2_rn(di * o.z, di * o.w);
        uint2 pk;
        pk.x = *(unsigned int*)&o01;
        pk.y = *(unsigned int*)&o23;
        *(uint2*)(outh + ((size_t)i << 4) + (q << 2)) = pk;
    } else {
        out4[(size_t)i * 4 + q] = r;
    }
}

extern "C" void kernel_launch(void* const* d_in, const int* in_sizes, int n_in,
                              void* d_out, int out_size, void* d_ws, size_t ws_size,
                              hipStream_t stream) {
    const float* x  = (const float*)d_in[0];   // [n, 54]
    const int*   ei = (const int*)d_in[1];     // [2, E]
    const float* W1 = (const float*)d_in[2];   // [54, 16]
    const float* b1 = (const float*)d_in[3];   // [16]
    const float* W2 = (const float*)d_in[4];   // [16, 16]
    const float* b2 = (const float*)d_in[5];   // [16]
    float* out = (float*)d_out;

    const int E = in_sizes[1] / 2;             // 3,200,000
    const int n = in_sizes[0] / FIN;           // 100,000
    const int* src = ei;
    const int* dst = ei + E;
    const int nb = (n + BNODES - 1) >> BSHIFT; // 782 buckets
    const int M = nb * NB_BLK;                 // 200,192 counters

    char* w = (char*)d_ws;
    float* dinv     = (float*)w;               w += (size_t)n * 4;
    int*   gh       = (int*)w;                 w += (size_t)M * 4;
    int*   bsum     = (int*)w;                 w += 512 * 4;
    int*   segstart = (int*)w;                 w += 1024 * 4;
    int*   cs       = (int*)w;                 w += (size_t)n * 4;
    char*  X        = w;                       // 12.8 MB shared region:
    unsigned int* binned = (unsigned int*)X;   //   build: binned[E]
    __half* hA      = (__half*)X;              //   later: hA[16n] fp16 (binned dead)
    __half* hB      = (__half*)(X + (size_t)n * HDIM * 2);
    {
        size_t xsz = (size_t)E * 4;
        size_t hsz = (size_t)n * HDIM * 4;     // hA+hB fp16
        w = X + (xsz > hsz ? xsz : hsz);
    }
    unsigned int* col = (unsigned int*)w;      // E u32 (12.8 MB)

    const int B = 256;
    const int nscan = (M + 4095) >> 12;        // 49

    // --- build: two-level counting sort -> CSR (col, cs) + dinv ---
    hist_kernel<<<NB_BLK, FBT, 0, stream>>>(dst, gh, E, nb);
    scan1_kernel<<<nscan, 256, 0, stream>>>(gh, bsum, M);
    scan2_kernel<<<1, 512, 0, stream>>>(bsum, nscan);
    scan3_kernel<<<(M + B - 1) / B, B, 0, stream>>>(gh, bsum, segstart, nb, E, M);
    fill_binned_kernel<<<NB_BLK, FBT, 0, stream>>>(src, dst, gh, binned, E, nb);
    local_sort_kernel<<<nb, LST, 0, stream>>>(binned, segstart, col, cs, dinv, n);

    // --- layer 1 transform (pre-scaled by dinv, fp16 out); binned dead ---
    gemm_kernel<<<(n + GTILE - 1) / GTILE, B, 0, stream>>>(x, W1, dinv, hA, n);

    // --- layer 1 gather + relu + fused @W2 (pre-scaled, fp16) -> hB ---
    gather_kernel<true><<<(n * 4 + B - 1) / B, B, 0, stream>>>(
        col, cs, hA, dinv, b1, W2, hB, nullptr, n, E);

    // --- layer 2 gather + bias + relu -> out (f32) ---
    gather_kernel<false><<<(n * 4 + B - 1) / B, B, 0, stream>>>(
        col, cs, hB, dinv, b2, nullptr, nullptr, (float4*)out, n, E);
}